// Round 4
// baseline (233.374 us; speedup 1.0000x reference)
//
#include <hip/hip_runtime.h>

// PositionAttentionModule: B=2, C=64, Cr=8, N=8192
// Single-head attention: d_qk=8, d_v=64, seq=8192 per batch.
// out[b,c,m] = alpha * (sum_n softmax_n(Q[m].K[n]) * V[c,n]) + x[b,c,m]
//
// R4: attn = depth-2 prefetch + 2x-unrolled stripe loop (two independent
// compute chains per wave); proj = c-split-4 with shuffle-butterfly merge
// (4 waves/CU instead of 1).

#define NB   2
#define CH   64
#define CR   8
#define NPOS 8192
#define QB   64

typedef __attribute__((ext_vector_type(8)))  __bf16 bf16x8;
typedef __attribute__((ext_vector_type(16))) float  f32x16;

__device__ inline unsigned pk_bf(float lo, float hi) {
    unsigned r;
    asm("v_cvt_pk_bf16_f32 %0, %1, %2" : "=v"(r) : "v"(lo), "v"(hi));
    return r;
}
__device__ inline unsigned short f2bf(float v) {
    return (unsigned short)(pk_bf(v, 0.f) & 0xFFFFu);
}
union U4B { uint4 u; bf16x8 b; };
__device__ inline bf16x8 as_bf(uint4 u) { U4B x; x.u = u; return x.b; }

// ---------------- projection kernel ----------------
// grid 256 x 256 threads: 4 threads (lane quad) per position, 16 in-channels
// each; partials merged via 2-round shfl_xor butterfly.
// Outputs: Qb (pre-scaled by log2e), Kb bf16 [B][N][8]; VTb bf16 [B][64][N].
__global__ __launch_bounds__(256) void proj_kernel(
    const float* __restrict__ x,
    const float* __restrict__ w_b, const float* __restrict__ b_b,
    const float* __restrict__ w_c, const float* __restrict__ b_c,
    const float* __restrict__ w_d, const float* __restrict__ b_d,
    unsigned short* __restrict__ Qb, unsigned short* __restrict__ Kb,
    unsigned short* __restrict__ VTb)
{
    __shared__ float swb[CH][CR];   // transposed: [c][r]
    __shared__ float swc[CH][CR];
    __shared__ float swd[CH][CH];   // transposed: [c][o]
    for (int i = threadIdx.x; i < CR * CH; i += 256) {
        int r = i / CH, c = i % CH;
        swb[c][r] = w_b[i];
        swc[c][r] = w_c[i];
    }
    for (int i = threadIdx.x; i < CH * CH; i += 256) {
        int o = i / CH, c = i % CH;
        swd[c][o] = w_d[i];
    }
    __syncthreads();

    const int tid = threadIdx.x;
    const int qt  = tid & 3;                  // c-quarter (lane quad)
    const int p   = blockIdx.x * 64 + (tid >> 2);
    const int b   = p >> 13;                  // / NPOS
    const int n   = p & (NPOS - 1);
    const float* xp = x + (size_t)b * CH * NPOS + (size_t)(qt * 16) * NPOS + n;

    float q[CR], k[CR];
    float4 v4[16];
    #pragma unroll
    for (int r = 0; r < CR; ++r) { q[r] = 0.f; k[r] = 0.f; }
    #pragma unroll
    for (int o = 0; o < 16; ++o) v4[o] = make_float4(0.f, 0.f, 0.f, 0.f);

    #pragma unroll
    for (int i = 0; i < 16; ++i) {
        float xv = xp[(size_t)i * NPOS];
        const int c = qt * 16 + i;
        const float4* wb4 = (const float4*)&swb[c][0];
        const float4* wc4 = (const float4*)&swc[c][0];
        #pragma unroll
        for (int r4 = 0; r4 < CR / 4; ++r4) {
            float4 wq = wb4[r4], wk = wc4[r4];
            q[r4*4+0] += wq.x * xv; q[r4*4+1] += wq.y * xv;
            q[r4*4+2] += wq.z * xv; q[r4*4+3] += wq.w * xv;
            k[r4*4+0] += wk.x * xv; k[r4*4+1] += wk.y * xv;
            k[r4*4+2] += wk.z * xv; k[r4*4+3] += wk.w * xv;
        }
        const float4* wd4 = (const float4*)&swd[c][0];
        #pragma unroll
        for (int o = 0; o < 16; ++o) {
            float4 w = wd4[o];
            v4[o].x += w.x * xv; v4[o].y += w.y * xv;
            v4[o].z += w.z * xv; v4[o].w += w.w * xv;
        }
    }

    // butterfly merge over the 4 quarters (lanes ^1, ^2)
    #pragma unroll
    for (int r = 0; r < CR; ++r) {
        q[r] += __shfl_xor(q[r], 1); q[r] += __shfl_xor(q[r], 2);
        k[r] += __shfl_xor(k[r], 1); k[r] += __shfl_xor(k[r], 2);
    }
    #pragma unroll
    for (int o = 0; o < 16; ++o) {
        v4[o].x += __shfl_xor(v4[o].x, 1); v4[o].x += __shfl_xor(v4[o].x, 2);
        v4[o].y += __shfl_xor(v4[o].y, 1); v4[o].y += __shfl_xor(v4[o].y, 2);
        v4[o].z += __shfl_xor(v4[o].z, 1); v4[o].z += __shfl_xor(v4[o].z, 2);
        v4[o].w += __shfl_xor(v4[o].w, 1); v4[o].w += __shfl_xor(v4[o].w, 2);
    }

    if (qt == 0) {
        const float L2E = 1.4426950408889634f;   // fold softmax exp -> exp2
        float qv[CR], kv[CR];
        #pragma unroll
        for (int r = 0; r < CR; ++r) {
            qv[r] = (q[r] + b_b[r]) * L2E;
            kv[r] = k[r] + b_c[r];
        }
        *(uint4*)(Qb + (size_t)p * CR) =
            make_uint4(pk_bf(qv[0], qv[1]), pk_bf(qv[2], qv[3]),
                       pk_bf(qv[4], qv[5]), pk_bf(qv[6], qv[7]));
        *(uint4*)(Kb + (size_t)p * CR) =
            make_uint4(pk_bf(kv[0], kv[1]), pk_bf(kv[2], kv[3]),
                       pk_bf(kv[4], kv[5]), pk_bf(kv[6], kv[7]));
    }

    // V^T: lane writes its own quarter's 16 channels (compile-time reg idx)
    size_t vtbase = (size_t)b * CH * NPOS + n;
    #pragma unroll
    for (int o = 0; o < 16; ++o) {
        if ((o >> 2) == qt) {
            VTb[vtbase + (size_t)(o*4+0) * NPOS] = f2bf(v4[o].x + b_d[o*4+0]);
            VTb[vtbase + (size_t)(o*4+1) * NPOS] = f2bf(v4[o].y + b_d[o*4+1]);
            VTb[vtbase + (size_t)(o*4+2) * NPOS] = f2bf(v4[o].z + b_d[o*4+2]);
            VTb[vtbase + (size_t)(o*4+3) * NPOS] = f2bf(v4[o].w + b_d[o*4+3]);
        }
    }
}

// ---------------- fused MFMA flash-attention ----------------
// grid = 256 blocks (B * N/QB), 1024 threads = 16 waves = (qh x kh[0..7]).
// Wave (qh,kh): 32-query tile, key slice kh of each 256-key stripe, all 64
// channels. Depth-2 prefetch with two register buffer sets, 2x unroll.
__global__ __launch_bounds__(1024, 4) void attn_kernel(
    const unsigned short* __restrict__ Qb, const unsigned short* __restrict__ Kb,
    const unsigned short* __restrict__ VTb, const float* __restrict__ x,
    const float* __restrict__ alpha, float* __restrict__ out)
{
    __shared__ float mbuf[4 * 2080];   // 4 merge regions: 2 tiles*1024 + 32 den

    const int tid = threadIdx.x;
    const int w   = tid >> 6;
    const int l   = tid & 63;
    const int li  = l & 31;
    const int h   = l >> 5;
    const int qh  = w & 1;
    const int kh  = w >> 1;            // 0..7: key slice
    const int blk = blockIdx.x;
    const int b   = blk >> 7;
    const int q0  = (blk & 127) * QB;
    const int m   = q0 + 32 * qh + li;

    const f32x16 z16 = {0,0,0,0,0,0,0,0,0,0,0,0,0,0,0,0};
    const uint4 zero4 = make_uint4(0, 0, 0, 0);

    // Q B-fragment: B[d][q]: q = lane&31, d = 8h+j (d>=8 -> zero pad)
    uint4 qf = zero4;
    if (h == 0) qf = *(const uint4*)(Qb + ((size_t)b * NPOS + m) * CR);

    f32x16 acc0 = z16, acc1 = z16;
    float dn0 = 0.f, dn1 = 0.f, dn2 = 0.f, dn3 = 0.f;

    const unsigned short* kb  = Kb  + ((size_t)b * NPOS + kh * 32 + li) * CR;
    const unsigned short* v00 = VTb + ((size_t)(b * CH) + li) * NPOS + kh * 32 + 8 * h;
    const unsigned short* v10 = v00 + (size_t)32 * NPOS;

#define LOADS(S, KF, A00, A01, A10, A11)                               \
    {   size_t off_ = (size_t)(S) * 256;                               \
        if (h == 0) KF = *(const uint4*)(kb + off_ * CR);              \
        A00 = *(const uint4*)(v00 + off_);                             \
        A01 = *(const uint4*)(v00 + off_ + 16);                        \
        A10 = *(const uint4*)(v10 + off_);                             \
        A11 = *(const uint4*)(v10 + off_ + 16);                        }

#define COMPUTE(KF, A00, A01, A10, A11)                                            \
    {   f32x16 sv = __builtin_amdgcn_mfma_f32_32x32x16_bf16(as_bf(KF), as_bf(qf),  \
                                                            z16, 0, 0, 0);         \
        float p_[16];                                                              \
        _Pragma("unroll")                                                          \
        for (int r_ = 0; r_ < 16; ++r_) p_[r_] = __builtin_amdgcn_exp2f(sv[r_]);   \
        dn0 += (p_[0]  + p_[1])  + (p_[2]  + p_[3]);                               \
        dn1 += (p_[4]  + p_[5])  + (p_[6]  + p_[7]);                               \
        dn2 += (p_[8]  + p_[9])  + (p_[10] + p_[11]);                              \
        dn3 += (p_[12] + p_[13]) + (p_[14] + p_[15]);                              \
        unsigned pa0 = pk_bf(p_[0],  p_[1]),  pa1 = pk_bf(p_[2],  p_[3]);          \
        unsigned pb0 = pk_bf(p_[4],  p_[5]),  pb1 = pk_bf(p_[6],  p_[7]);          \
        unsigned pc0 = pk_bf(p_[8],  p_[9]),  pc1 = pk_bf(p_[10], p_[11]);         \
        unsigned pd0 = pk_bf(p_[12], p_[13]), pd1 = pk_bf(p_[14], p_[15]);         \
        asm("v_permlane32_swap_b32 %0, %1" : "+v"(pa0), "+v"(pb0));                \
        asm("v_permlane32_swap_b32 %0, %1" : "+v"(pa1), "+v"(pb1));                \
        asm("v_permlane32_swap_b32 %0, %1" : "+v"(pc0), "+v"(pd0));                \
        asm("v_permlane32_swap_b32 %0, %1" : "+v"(pc1), "+v"(pd1));                \
        uint4 BA = make_uint4(pa0, pa1, pb0, pb1);                                 \
        uint4 BB = make_uint4(pc0, pc1, pd0, pd1);                                 \
        acc0 = __builtin_amdgcn_mfma_f32_32x32x16_bf16(as_bf(A00), as_bf(BA), acc0, 0, 0, 0); \
        acc0 = __builtin_amdgcn_mfma_f32_32x32x16_bf16(as_bf(A01), as_bf(BB), acc0, 0, 0, 0); \
        acc1 = __builtin_amdgcn_mfma_f32_32x32x16_bf16(as_bf(A10), as_bf(BA), acc1, 0, 0, 0); \
        acc1 = __builtin_amdgcn_mfma_f32_32x32x16_bf16(as_bf(A11), as_bf(BB), acc1, 0, 0, 0); }

    uint4 kfA = zero4, a00A, a01A, a10A, a11A;
    uint4 kfB = zero4, a00B, a01B, a10B, a11B;
    LOADS(0, kfA, a00A, a01A, a10A, a11A);
    LOADS(1, kfB, a00B, a01B, a10B, a11B);

    for (int j = 0; j < 16; ++j) {
        COMPUTE(kfA, a00A, a01A, a10A, a11A);
        {
            int s = 2 * j + 2; if (s > 31) s = 31;   // tail: redundant reload
            LOADS(s, kfA, a00A, a01A, a10A, a11A);
        }
        COMPUTE(kfB, a00B, a01B, a10B, a11B);
        {
            int s = 2 * j + 3; if (s > 31) s = 31;
            LOADS(s, kfB, a00B, a01B, a10B, a11B);
        }
    }
#undef LOADS
#undef COMPUTE

    float den = (dn0 + dn1) + (dn2 + dn3);
    den += __shfl_xor(den, 32);        // other half holds the other 16 key-rows

    // ---- kh tree-merge (qh groups serialized to fit 4 LDS regions) ----
    for (int g = 0; g < 2; ++g) {
        for (int step = 4; step >= 1; step >>= 1) {
            if (qh == g && kh >= step && kh < 2 * step) {
                float* rg = mbuf + (kh - step) * 2080;
                #pragma unroll
                for (int r = 0; r < 16; ++r) {
                    rg[r * 64 + l]        = acc0[r];
                    rg[1024 + r * 64 + l] = acc1[r];
                }
                if (h == 0) rg[2048 + li] = den;
            }
            __syncthreads();
            if (qh == g && kh < step) {
                const float* rg = mbuf + kh * 2080;
                #pragma unroll
                for (int r = 0; r < 16; ++r) {
                    acc0[r] += rg[r * 64 + l];
                    acc1[r] += rg[1024 + r * 64 + l];
                }
                if (h == 0) den += rg[2048 + li];
            }
            __syncthreads();
        }
    }
    if (kh == 0) {
        float* rg = mbuf + qh * 2080;
        #pragma unroll
        for (int r = 0; r < 16; ++r) {
            rg[r * 64 + l]        = acc0[r];
            rg[1024 + r * 64 + l] = acc1[r];
        }
        if (h == 0) rg[2048 + li] = den;
    }
    __syncthreads();

    // ---- epilogue: all 1024 threads, coalesced float4 ----
    {
        const int c   = tid >> 4;          // 0..63
        const int q4  = (tid & 15) * 4;    // 0..60
        const int qhe = q4 >> 5, qlo = q4 & 31;
        const int tile = c >> 5, c5 = c & 31;
        const int hh  = (c5 >> 2) & 1;
        const int r   = (c5 & 3) | ((c5 >> 3) << 2);
        const float* rg = mbuf + qhe * 2080;
        float4 a   = *(const float4*)&rg[tile * 1024 + r * 64 + 32 * hh + qlo];
        float4 dnv = *(const float4*)&rg[2048 + qlo];
        float  al  = alpha[0];
        size_t xo  = ((size_t)(b * CH + c)) * NPOS + q0 + q4;
        float4 xv  = *(const float4*)&x[xo];
        float4 o;
        o.x = a.x * (al / dnv.x) + xv.x;
        o.y = a.y * (al / dnv.y) + xv.y;
        o.z = a.z * (al / dnv.z) + xv.z;
        o.w = a.w * (al / dnv.w) + xv.w;
        *(float4*)&out[xo] = o;
    }
}

extern "C" void kernel_launch(void* const* d_in, const int* in_sizes, int n_in,
                              void* d_out, int out_size, void* d_ws, size_t ws_size,
                              hipStream_t stream) {
    const float* x     = (const float*)d_in[0];
    const float* w_b   = (const float*)d_in[1];
    const float* b_b   = (const float*)d_in[2];
    const float* w_c   = (const float*)d_in[3];
    const float* b_c   = (const float*)d_in[4];
    const float* w_d   = (const float*)d_in[5];
    const float* b_d   = (const float*)d_in[6];
    const float* alpha = (const float*)d_in[7];
    float* out = (float*)d_out;

    unsigned short* Qw  = (unsigned short*)d_ws;                 // 256 KB
    unsigned short* Kw  = Qw + (size_t)NB * NPOS * CR;           // 256 KB
    unsigned short* VTw = Kw + (size_t)NB * NPOS * CR;           // 2 MB

    proj_kernel<<<NB * NPOS * 4 / 256, 256, 0, stream>>>(x, w_b, b_b, w_c, b_c, w_d, b_d, Qw, Kw, VTw);
    attn_kernel<<<NB * NPOS / QB, 1024, 0, stream>>>(Qw, Kw, VTw, x, alpha, out);
}

// Round 5
// 61.407 us; speedup vs baseline: 3.8004x; 3.8004x over previous
//
#include <hip/hip_runtime.h>

// PositionAttentionModule: B=2, C=64, Cr=8, N=8192
// Single-head attention: d_qk=8, d_v=64, seq=8192 per batch.
// out[b,c,m] = alpha * (sum_n softmax_n(Q[m].K[n]) * V[c,n]) + x[b,c,m]
//
// R5 = R3 structure (16 waves = qh x kh[0..7], in-register softmax via
// cvt_pk+permlane32_swap, reg K-prefetch) + block-cooperative LDS V staging:
// 256-key stripe (64x256 bf16 = 32KB) double-buffered, reg->LDS with
// XOR-swizzled ds_write (s' = s ^ (row&7)), ds_read_b128 fragments.
// R4's depth-2 reg pipeline spilled to scratch (WRITE_SIZE 179MB) - reverted.

#define NB   2
#define CH   64
#define CR   8
#define NPOS 8192
#define QB   64
#define NSTRIPE (NPOS / 256)   // 32

typedef __attribute__((ext_vector_type(8)))  __bf16 bf16x8;
typedef __attribute__((ext_vector_type(16))) float  f32x16;

__device__ inline unsigned pk_bf(float lo, float hi) {
    unsigned r;
    asm("v_cvt_pk_bf16_f32 %0, %1, %2" : "=v"(r) : "v"(lo), "v"(hi));
    return r;
}
__device__ inline unsigned short f2bf(float v) {
    return (unsigned short)(pk_bf(v, 0.f) & 0xFFFFu);
}
union U4B { uint4 u; bf16x8 b; };
__device__ inline bf16x8 as_bf(uint4 u) { U4B x; x.u = u; return x.b; }

// ---------------- projection kernel (unchanged from R4) ----------------
__global__ __launch_bounds__(256) void proj_kernel(
    const float* __restrict__ x,
    const float* __restrict__ w_b, const float* __restrict__ b_b,
    const float* __restrict__ w_c, const float* __restrict__ b_c,
    const float* __restrict__ w_d, const float* __restrict__ b_d,
    unsigned short* __restrict__ Qb, unsigned short* __restrict__ Kb,
    unsigned short* __restrict__ VTb)
{
    __shared__ float swb[CH][CR];
    __shared__ float swc[CH][CR];
    __shared__ float swd[CH][CH];
    for (int i = threadIdx.x; i < CR * CH; i += 256) {
        int r = i / CH, c = i % CH;
        swb[c][r] = w_b[i];
        swc[c][r] = w_c[i];
    }
    for (int i = threadIdx.x; i < CH * CH; i += 256) {
        int o = i / CH, c = i % CH;
        swd[c][o] = w_d[i];
    }
    __syncthreads();

    const int tid = threadIdx.x;
    const int qt  = tid & 3;
    const int p   = blockIdx.x * 64 + (tid >> 2);
    const int b   = p >> 13;
    const int n   = p & (NPOS - 1);
    const float* xp = x + (size_t)b * CH * NPOS + (size_t)(qt * 16) * NPOS + n;

    float q[CR], k[CR];
    float4 v4[16];
    #pragma unroll
    for (int r = 0; r < CR; ++r) { q[r] = 0.f; k[r] = 0.f; }
    #pragma unroll
    for (int o = 0; o < 16; ++o) v4[o] = make_float4(0.f, 0.f, 0.f, 0.f);

    #pragma unroll
    for (int i = 0; i < 16; ++i) {
        float xv = xp[(size_t)i * NPOS];
        const int c = qt * 16 + i;
        const float4* wb4 = (const float4*)&swb[c][0];
        const float4* wc4 = (const float4*)&swc[c][0];
        #pragma unroll
        for (int r4 = 0; r4 < CR / 4; ++r4) {
            float4 wq = wb4[r4], wk = wc4[r4];
            q[r4*4+0] += wq.x * xv; q[r4*4+1] += wq.y * xv;
            q[r4*4+2] += wq.z * xv; q[r4*4+3] += wq.w * xv;
            k[r4*4+0] += wk.x * xv; k[r4*4+1] += wk.y * xv;
            k[r4*4+2] += wk.z * xv; k[r4*4+3] += wk.w * xv;
        }
        const float4* wd4 = (const float4*)&swd[c][0];
        #pragma unroll
        for (int o = 0; o < 16; ++o) {
            float4 w = wd4[o];
            v4[o].x += w.x * xv; v4[o].y += w.y * xv;
            v4[o].z += w.z * xv; v4[o].w += w.w * xv;
        }
    }

    #pragma unroll
    for (int r = 0; r < CR; ++r) {
        q[r] += __shfl_xor(q[r], 1); q[r] += __shfl_xor(q[r], 2);
        k[r] += __shfl_xor(k[r], 1); k[r] += __shfl_xor(k[r], 2);
    }
    #pragma unroll
    for (int o = 0; o < 16; ++o) {
        v4[o].x += __shfl_xor(v4[o].x, 1); v4[o].x += __shfl_xor(v4[o].x, 2);
        v4[o].y += __shfl_xor(v4[o].y, 1); v4[o].y += __shfl_xor(v4[o].y, 2);
        v4[o].z += __shfl_xor(v4[o].z, 1); v4[o].z += __shfl_xor(v4[o].z, 2);
        v4[o].w += __shfl_xor(v4[o].w, 1); v4[o].w += __shfl_xor(v4[o].w, 2);
    }

    if (qt == 0) {
        const float L2E = 1.4426950408889634f;
        float qv[CR], kv[CR];
        #pragma unroll
        for (int r = 0; r < CR; ++r) {
            qv[r] = (q[r] + b_b[r]) * L2E;
            kv[r] = k[r] + b_c[r];
        }
        *(uint4*)(Qb + (size_t)p * CR) =
            make_uint4(pk_bf(qv[0], qv[1]), pk_bf(qv[2], qv[3]),
                       pk_bf(qv[4], qv[5]), pk_bf(qv[6], qv[7]));
        *(uint4*)(Kb + (size_t)p * CR) =
            make_uint4(pk_bf(kv[0], kv[1]), pk_bf(kv[2], kv[3]),
                       pk_bf(kv[4], kv[5]), pk_bf(kv[6], kv[7]));
    }

    size_t vtbase = (size_t)b * CH * NPOS + n;
    #pragma unroll
    for (int o = 0; o < 16; ++o) {
        if ((o >> 2) == qt) {
            VTb[vtbase + (size_t)(o*4+0) * NPOS] = f2bf(v4[o].x + b_d[o*4+0]);
            VTb[vtbase + (size_t)(o*4+1) * NPOS] = f2bf(v4[o].y + b_d[o*4+1]);
            VTb[vtbase + (size_t)(o*4+2) * NPOS] = f2bf(v4[o].z + b_d[o*4+2]);
            VTb[vtbase + (size_t)(o*4+3) * NPOS] = f2bf(v4[o].w + b_d[o*4+3]);
        }
    }
}

// ---------------- fused MFMA flash-attention ----------------
// grid = 256 blocks, 1024 threads = 16 waves = (qh in {0,1}, kh in {0..7}).
// V stripe (64 rows x 256 keys bf16) double-buffered in LDS, XOR-swizzled.
__global__ __launch_bounds__(1024, 4) void attn_kernel(
    const unsigned short* __restrict__ Qb, const unsigned short* __restrict__ Kb,
    const unsigned short* __restrict__ VTb, const float* __restrict__ x,
    const float* __restrict__ alpha, float* __restrict__ out)
{
    __shared__ uint4 sbuf[4096];           // 2 x 32KB stripe buffers
    float* mbuf = (float*)sbuf;            // merge regions alias (dead after loop)

    const int tid = threadIdx.x;
    const int w   = tid >> 6;
    const int l   = tid & 63;
    const int li  = l & 31;
    const int h   = l >> 5;
    const int qh  = w & 1;
    const int kh  = w >> 1;
    const int blk = (blockIdx.x & 7) * 32 + (blockIdx.x >> 3);   // XCD swizzle
    const int b   = blk >> 7;
    const int q0  = (blk & 127) * QB;
    const int m   = q0 + 32 * qh + li;

    const f32x16 z16 = {0,0,0,0,0,0,0,0,0,0,0,0,0,0,0,0};
    const uint4 zero4 = make_uint4(0, 0, 0, 0);

    uint4 qf = zero4;
    if (h == 0) qf = *(const uint4*)(Qb + ((size_t)b * NPOS + m) * CR);

    f32x16 acc0 = z16, acc1 = z16;
    float dn0 = 0.f, dn1 = 0.f, dn2 = 0.f, dn3 = 0.f;

    // K: per-wave slice, reg-prefetched one stripe ahead (coalesced 512B)
    const unsigned short* kb = Kb + ((size_t)b * NPOS + kh * 32 + li) * CR;

    // V staging: thread t covers row = t>>4, linear global slots (t&15), 16+(t&15);
    // LDS slot' = s ^ (row&7)  (write-side swizzle; read applies same XOR)
    const int srow  = tid >> 4;
    const int sslt  = tid & 15;
    const unsigned short* vg = VTb + ((size_t)(b * CH + srow)) * NPOS + sslt * 8;
    const int iw0 = srow * 32 + (sslt ^ (srow & 7));   // 16B-slot index

    // fragment read indices (16B-slot units): rows li / 32+li, slots kh*4+{h, 2+h}
    const int s0  = kh * 4 + h;
    const int i00 = li * 32 + (s0 ^ (li & 7));
    const int i01 = li * 32 + ((s0 + 2) ^ (li & 7));

    // ---- prologue: stage stripe 0, load K(0) ----
    {
        uint4 p0 = *(const uint4*)(vg);
        uint4 p1 = *(const uint4*)(vg + 128);
        sbuf[iw0]      = p0;
        sbuf[iw0 + 16] = p1;
    }
    uint4 kf = zero4, kf_n = zero4;
    if (h == 0) kf = *(const uint4*)kb;
    __syncthreads();

    for (int t = 0; t < NSTRIPE; ++t) {
        uint4 st0, st1;
        const bool more = (t + 1 < NSTRIPE);
        if (more) {                         // issue next-stripe loads (T14 split)
            const size_t off = (size_t)(t + 1) * 256;
            st0 = *(const uint4*)(vg + off);
            st1 = *(const uint4*)(vg + off + 128);
            if (h == 0) kf_n = *(const uint4*)(kb + off * CR);
        }

        // ---- compute stripe t ----
        const int base = (t & 1) * 2048;
        f32x16 sv = __builtin_amdgcn_mfma_f32_32x32x16_bf16(as_bf(kf), as_bf(qf), z16, 0, 0, 0);
        uint4 a00 = sbuf[base + i00];
        uint4 a01 = sbuf[base + i01];
        uint4 a10 = sbuf[base + 1024 + i00];
        uint4 a11 = sbuf[base + 1024 + i01];

        float p[16];
        #pragma unroll
        for (int r = 0; r < 16; ++r) p[r] = __builtin_amdgcn_exp2f(sv[r]);
        dn0 += (p[0]  + p[1])  + (p[2]  + p[3]);
        dn1 += (p[4]  + p[5])  + (p[6]  + p[7]);
        dn2 += (p[8]  + p[9])  + (p[10] + p[11]);
        dn3 += (p[12] + p[13]) + (p[14] + p[15]);

        unsigned pa0 = pk_bf(p[0],  p[1]),  pa1 = pk_bf(p[2],  p[3]);
        unsigned pb0 = pk_bf(p[4],  p[5]),  pb1 = pk_bf(p[6],  p[7]);
        unsigned pc0 = pk_bf(p[8],  p[9]),  pc1 = pk_bf(p[10], p[11]);
        unsigned pd0 = pk_bf(p[12], p[13]), pd1 = pk_bf(p[14], p[15]);
        asm("v_permlane32_swap_b32 %0, %1" : "+v"(pa0), "+v"(pb0));
        asm("v_permlane32_swap_b32 %0, %1" : "+v"(pa1), "+v"(pb1));
        asm("v_permlane32_swap_b32 %0, %1" : "+v"(pc0), "+v"(pd0));
        asm("v_permlane32_swap_b32 %0, %1" : "+v"(pc1), "+v"(pd1));
        uint4 BA = make_uint4(pa0, pa1, pb0, pb1);
        uint4 BB = make_uint4(pc0, pc1, pd0, pd1);

        acc0 = __builtin_amdgcn_mfma_f32_32x32x16_bf16(as_bf(a00), as_bf(BA), acc0, 0, 0, 0);
        acc0 = __builtin_amdgcn_mfma_f32_32x32x16_bf16(as_bf(a01), as_bf(BB), acc0, 0, 0, 0);
        acc1 = __builtin_amdgcn_mfma_f32_32x32x16_bf16(as_bf(a10), as_bf(BA), acc1, 0, 0, 0);
        acc1 = __builtin_amdgcn_mfma_f32_32x32x16_bf16(as_bf(a11), as_bf(BB), acc1, 0, 0, 0);

        // ---- write next stripe (loads had the whole compute to land) ----
        if (more) {
            const int nb = ((t + 1) & 1) * 2048;
            sbuf[nb + iw0]      = st0;
            sbuf[nb + iw0 + 16] = st1;
        }
        __syncthreads();
        kf = kf_n;
    }

    float den = (dn0 + dn1) + (dn2 + dn3);
    den += __shfl_xor(den, 32);

    // ---- kh tree-merge (qh groups serialized, 4 LDS regions) ----
    for (int g = 0; g < 2; ++g) {
        for (int step = 4; step >= 1; step >>= 1) {
            if (qh == g && kh >= step && kh < 2 * step) {
                float* rg = mbuf + (kh - step) * 2080;
                #pragma unroll
                for (int r = 0; r < 16; ++r) {
                    rg[r * 64 + l]        = acc0[r];
                    rg[1024 + r * 64 + l] = acc1[r];
                }
                if (h == 0) rg[2048 + li] = den;
            }
            __syncthreads();
            if (qh == g && kh < step) {
                const float* rg = mbuf + kh * 2080;
                #pragma unroll
                for (int r = 0; r < 16; ++r) {
                    acc0[r] += rg[r * 64 + l];
                    acc1[r] += rg[1024 + r * 64 + l];
                }
                if (h == 0) den += rg[2048 + li];
            }
            __syncthreads();
        }
    }
    if (kh == 0) {
        float* rg = mbuf + qh * 2080;
        #pragma unroll
        for (int r = 0; r < 16; ++r) {
            rg[r * 64 + l]        = acc0[r];
            rg[1024 + r * 64 + l] = acc1[r];
        }
        if (h == 0) rg[2048 + li] = den;
    }
    __syncthreads();

    // ---- epilogue: coalesced float4 ----
    {
        const int c   = tid >> 4;
        const int q4  = (tid & 15) * 4;
        const int qhe = q4 >> 5, qlo = q4 & 31;
        const int tile = c >> 5, c5 = c & 31;
        const int hh  = (c5 >> 2) & 1;
        const int r   = (c5 & 3) | ((c5 >> 3) << 2);
        const float* rg = mbuf + qhe * 2080;
        float4 a   = *(const float4*)&rg[tile * 1024 + r * 64 + 32 * hh + qlo];
        float4 dnv = *(const float4*)&rg[2048 + qlo];
        float  al  = alpha[0];
        size_t xo  = ((size_t)(b * CH + c)) * NPOS + q0 + q4;
        float4 xv  = *(const float4*)&x[xo];
        float4 o;
        o.x = a.x * (al / dnv.x) + xv.x;
        o.y = a.y * (al / dnv.y) + xv.y;
        o.z = a.z * (al / dnv.z) + xv.z;
        o.w = a.w * (al / dnv.w) + xv.w;
        *(float4*)&out[xo] = o;
    }
}

extern "C" void kernel_launch(void* const* d_in, const int* in_sizes, int n_in,
                              void* d_out, int out_size, void* d_ws, size_t ws_size,
                              hipStream_t stream) {
    const float* x     = (const float*)d_in[0];
    const float* w_b   = (const float*)d_in[1];
    const float* b_b   = (const float*)d_in[2];
    const float* w_c   = (const float*)d_in[3];
    const float* b_c   = (const float*)d_in[4];
    const float* w_d   = (const float*)d_in[5];
    const float* b_d   = (const float*)d_in[6];
    const float* alpha = (const float*)d_in[7];
    float* out = (float*)d_out;

    unsigned short* Qw  = (unsigned short*)d_ws;
    unsigned short* Kw  = Qw + (size_t)NB * NPOS * CR;
    unsigned short* VTw = Kw + (size_t)NB * NPOS * CR;

    proj_kernel<<<NB * NPOS * 4 / 256, 256, 0, stream>>>(x, w_b, b_b, w_c, b_c, w_d, b_d, Qw, Kw, VTw);
    attn_kernel<<<NB * NPOS / QB, 1024, 0, stream>>>(Qw, Kw, VTw, x, alpha, out);
}

// Round 6
// 47.532 us; speedup vs baseline: 4.9099x; 1.2919x over previous
//
#include <hip/hip_runtime.h>

// PositionAttentionModule: B=2, C=64, Cr=8, N=8192
// Single-head attention: d_qk=8, d_v=64, seq=8192 per batch.
// out[b,c,m] = alpha * (sum_n softmax_n(Q[m].K[n]) * V[c,n]) + x[b,c,m]
//
// R6:
//  - proj is now an MFMA GEMM: W~[96x64] (wd | wb*log2e | wc) held as reg
//    A-frags, X streamed as B-frags (fixes R5's 320-ds_read/wave weight
//    re-read bound).  b_c dropped (softmax-invariant: shifts each query's
//    logits by a constant).  b_d folded into attn epilogue (sum attn = 1).
//  - attn: KB=512 stripes (16 barriers), V staged via global_load_lds DMA
//    (linear LDS dest, XOR-swizzle moved to per-lane global source), two
//    32-key chunks per wave per stripe for intra-wave overlap.

#define NB   2
#define CH   64
#define CR   8
#define NPOS 8192
#define QB   64
#define KB2  512
#define NSTR (NPOS / KB2)   // 16

typedef __attribute__((ext_vector_type(8)))  __bf16 bf16x8;
typedef __attribute__((ext_vector_type(16))) float  f32x16;

__device__ inline unsigned pk_bf(float lo, float hi) {
    unsigned r;
    asm("v_cvt_pk_bf16_f32 %0, %1, %2" : "=v"(r) : "v"(lo), "v"(hi));
    return r;
}
__device__ inline unsigned short f2bf(float v) {
    return (unsigned short)(pk_bf(v, 0.f) & 0xFFFFu);
}
union U4B { uint4 u; bf16x8 b; };
__device__ inline bf16x8 as_bf(uint4 u) { U4B x; x.u = u; return x.b; }

// ---------------- projection kernel (MFMA) ----------------
// grid 256 x 128 thr (2 waves). Block covers 64 positions; wave covers 32.
// W~[96x64]: rows 0-63 = w_d, 64-71 = w_b*log2e, 72-79 = w_c, 80-95 unused.
// O[96 x n] = W~ . X ; V rows stored to VTb (no bias), Q/K packed per-n.
__global__ __launch_bounds__(128) void proj_kernel(
    const float* __restrict__ x,
    const float* __restrict__ w_b, const float* __restrict__ b_b,
    const float* __restrict__ w_c,
    const float* __restrict__ w_d,
    unsigned short* __restrict__ Qb, unsigned short* __restrict__ Kb,
    unsigned short* __restrict__ VTb)
{
    __shared__ unsigned short wt[96 * 64];
    const int tid = threadIdx.x;
    const float L2E = 1.4426950408889634f;
    for (int j = tid; j < 4096; j += 128) wt[j] = f2bf(w_d[j]);
    for (int j = tid; j < 512; j += 128) {
        wt[64 * 64 + j] = f2bf(w_b[j] * L2E);
        wt[72 * 64 + j] = f2bf(w_c[j]);
    }
    __syncthreads();

    const int w  = tid >> 6, l = tid & 63, li = l & 31, h = l >> 5;
    const int ng = blockIdx.x * 64 + w * 32;     // global position base
    const int b  = ng >> 13;
    const int n  = ng & (NPOS - 1);

    const f32x16 z16 = {0,0,0,0,0,0,0,0,0,0,0,0,0,0,0,0};

    // A-frags: W~[32o x 16k] per (tile, k-step); lane l: row=l&31, k=8h+j
    uint4 af[3][4];
    #pragma unroll
    for (int t = 0; t < 3; ++t)
        #pragma unroll
        for (int ks = 0; ks < 4; ++ks)
            af[t][ks] = *(const uint4*)&wt[(t * 32 + li) * 64 + ks * 16 + 8 * h];

    f32x16 acc0 = z16, acc1 = z16, acc2 = z16;
    #pragma unroll
    for (int ks = 0; ks < 4; ++ks) {
        float xr[8];
        #pragma unroll
        for (int j = 0; j < 8; ++j)
            xr[j] = x[(size_t)(b * CH + ks * 16 + 8 * h + j) * NPOS + n + li];
        uint4 bf = make_uint4(pk_bf(xr[0], xr[1]), pk_bf(xr[2], xr[3]),
                              pk_bf(xr[4], xr[5]), pk_bf(xr[6], xr[7]));
        acc0 = __builtin_amdgcn_mfma_f32_32x32x16_bf16(as_bf(af[0][ks]), as_bf(bf), acc0, 0, 0, 0);
        acc1 = __builtin_amdgcn_mfma_f32_32x32x16_bf16(as_bf(af[1][ks]), as_bf(bf), acc1, 0, 0, 0);
        acc2 = __builtin_amdgcn_mfma_f32_32x32x16_bf16(as_bf(af[2][ks]), as_bf(bf), acc2, 0, 0, 0);
    }

    // V epilogue: rows 0..63, C/D row = (r&3)+8*(r>>2)+4h
    #pragma unroll
    for (int r = 0; r < 16; ++r) {
        int crow = (r & 3) + 8 * (r >> 2) + 4 * h;
        VTb[(size_t)(b * CH + crow) * NPOS + n + li]      = f2bf(acc0[r]);
        VTb[(size_t)(b * CH + 32 + crow) * NPOS + n + li] = f2bf(acc1[r]);
    }

    // Q/K epilogue: acc2 r0..3 -> Q d=(r)+4h (rows 64..71); r4..7 -> K d=(r-4)+4h
    {
        float bb0 = b_b[4 * h + 0] * L2E, bb1 = b_b[4 * h + 1] * L2E;
        float bb2 = b_b[4 * h + 2] * L2E, bb3 = b_b[4 * h + 3] * L2E;
        unsigned q0p = pk_bf(acc2[0] + bb0, acc2[1] + bb1);
        unsigned q1p = pk_bf(acc2[2] + bb2, acc2[3] + bb3);
        unsigned k0p = pk_bf(acc2[4], acc2[5]);
        unsigned k1p = pk_bf(acc2[6], acc2[7]);
        // half-broadcast: after swap(a,b) with a=b=v: a = lo-half vals, b = hi-half vals
        unsigned qa0 = q0p, qb0 = q0p, qa1 = q1p, qb1 = q1p;
        asm("v_permlane32_swap_b32 %0, %1" : "+v"(qa0), "+v"(qb0));
        asm("v_permlane32_swap_b32 %0, %1" : "+v"(qa1), "+v"(qb1));
        unsigned ka0 = k0p, kb0 = k0p, ka1 = k1p, kb1 = k1p;
        asm("v_permlane32_swap_b32 %0, %1" : "+v"(ka0), "+v"(kb0));
        asm("v_permlane32_swap_b32 %0, %1" : "+v"(ka1), "+v"(kb1));
        if (h == 0) {
            *(uint4*)(Qb + (size_t)(b * NPOS + n + li) * CR) = make_uint4(qa0, qa1, qb0, qb1);
            *(uint4*)(Kb + (size_t)(b * NPOS + n + li) * CR) = make_uint4(ka0, ka1, kb0, kb1);
        }
    }
}

// ---------------- fused MFMA flash-attention ----------------
// grid = 256 blocks, 1024 threads = 16 waves = (qh in {0,1}, kh in {0..7}).
// V stripe (64 x 512 keys bf16 = 64KB) double-buffered, staged by
// global_load_lds DMA with source-side XOR swizzle.
__global__ __launch_bounds__(1024, 4) void attn_kernel(
    const unsigned short* __restrict__ Qb, const unsigned short* __restrict__ Kb,
    const unsigned short* __restrict__ VTb, const float* __restrict__ x,
    const float* __restrict__ alpha, const float* __restrict__ b_d,
    float* __restrict__ out)
{
    __shared__ uint4 sbuf[8192];           // 2 x 64KB stripe buffers
    float* mbuf = (float*)sbuf;            // merge regions alias (dead after loop)

    const int tid = threadIdx.x;
    const int w   = tid >> 6;
    const int l   = tid & 63;
    const int li  = l & 31;
    const int h   = l >> 5;
    const int qh  = w & 1;
    const int kh  = w >> 1;
    const int blk = (blockIdx.x & 7) * 32 + (blockIdx.x >> 3);   // XCD swizzle
    const int b   = blk >> 7;
    const int q0  = (blk & 127) * QB;
    const int m   = q0 + 32 * qh + li;

    const f32x16 z16 = {0,0,0,0,0,0,0,0,0,0,0,0,0,0,0,0};
    const uint4 zero4 = make_uint4(0, 0, 0, 0);

    uint4 qf = zero4;
    if (h == 0) qf = *(const uint4*)(Qb + ((size_t)b * NPOS + m) * CR);

    f32x16 acc0 = z16, acc1 = z16;
    float dn0 = 0.f, dn1 = 0.f, dn2 = 0.f, dn3 = 0.f;

    // K: wave keys = kh*64 + chunk*32 + li per stripe
    const unsigned short* kb0 = Kb + ((size_t)b * NPOS + kh * 64 + li) * CR;
    const unsigned short* kb1 = kb0 + 32 * CR;

    // DMA: wave w, round r stages row = r*16+w (row&7 == w&7 for all r).
    // LDS slot u = r*1024 + w*64 + l holds global slot (l&56)|((l&7)^(w&7)).
    const unsigned short* vg = VTb + ((size_t)(b * CH + w)) * NPOS
                             + (size_t)((l & 56) | ((l & 7) ^ (w & 7))) * 8;

#define STAGE(T) {                                                               \
    const unsigned short* g_ = vg + (size_t)(T) * KB2;                           \
    const int bb_ = ((T) & 1) * 65536 + w * 1024;                                \
    _Pragma("unroll")                                                            \
    for (int r_ = 0; r_ < 4; ++r_)                                               \
        __builtin_amdgcn_global_load_lds(                                        \
            (const __attribute__((address_space(1))) void*)(g_ + (size_t)r_ * 16 * NPOS), \
            (__attribute__((address_space(3))) void*)((char*)(void*)sbuf + bb_ + r_ * 16384), \
            16, 0, 0); }

    // fragment index (16B slots): row li (+2048 for ch 32..63), chunk ^4, sub ^2
    const int i0 = li * 64 + ((kh * 8 + h) ^ (li & 7));

#define CHUNK(IA, KF) {                                                                       \
    f32x16 sv = __builtin_amdgcn_mfma_f32_32x32x16_bf16(as_bf(KF), as_bf(qf), z16, 0, 0, 0);  \
    const int bs_ = (t & 1) * 4096;                                                           \
    uint4 a00 = sbuf[bs_ + (IA)];                                                             \
    uint4 a01 = sbuf[bs_ + ((IA) ^ 2)];                                                       \
    uint4 a10 = sbuf[bs_ + 2048 + (IA)];                                                      \
    uint4 a11 = sbuf[bs_ + 2048 + ((IA) ^ 2)];                                                \
    float p_[16];                                                                             \
    _Pragma("unroll")                                                                         \
    for (int r_ = 0; r_ < 16; ++r_) p_[r_] = __builtin_amdgcn_exp2f(sv[r_]);                  \
    dn0 += (p_[0]  + p_[1])  + (p_[2]  + p_[3]);                                              \
    dn1 += (p_[4]  + p_[5])  + (p_[6]  + p_[7]);                                              \
    dn2 += (p_[8]  + p_[9])  + (p_[10] + p_[11]);                                             \
    dn3 += (p_[12] + p_[13]) + (p_[14] + p_[15]);                                             \
    unsigned pa0 = pk_bf(p_[0],  p_[1]),  pa1 = pk_bf(p_[2],  p_[3]);                         \
    unsigned pb0 = pk_bf(p_[4],  p_[5]),  pb1 = pk_bf(p_[6],  p_[7]);                         \
    unsigned pc0 = pk_bf(p_[8],  p_[9]),  pc1 = pk_bf(p_[10], p_[11]);                        \
    unsigned pd0 = pk_bf(p_[12], p_[13]), pd1 = pk_bf(p_[14], p_[15]);                        \
    asm("v_permlane32_swap_b32 %0, %1" : "+v"(pa0), "+v"(pb0));                               \
    asm("v_permlane32_swap_b32 %0, %1" : "+v"(pa1), "+v"(pb1));                               \
    asm("v_permlane32_swap_b32 %0, %1" : "+v"(pc0), "+v"(pd0));                               \
    asm("v_permlane32_swap_b32 %0, %1" : "+v"(pc1), "+v"(pd1));                               \
    uint4 BA = make_uint4(pa0, pa1, pb0, pb1);                                                \
    uint4 BB = make_uint4(pc0, pc1, pd0, pd1);                                                \
    acc0 = __builtin_amdgcn_mfma_f32_32x32x16_bf16(as_bf(a00), as_bf(BA), acc0, 0, 0, 0);     \
    acc0 = __builtin_amdgcn_mfma_f32_32x32x16_bf16(as_bf(a01), as_bf(BB), acc0, 0, 0, 0);     \
    acc1 = __builtin_amdgcn_mfma_f32_32x32x16_bf16(as_bf(a10), as_bf(BA), acc1, 0, 0, 0);     \
    acc1 = __builtin_amdgcn_mfma_f32_32x32x16_bf16(as_bf(a11), as_bf(BB), acc1, 0, 0, 0); }

    // ---- prologue ----
    STAGE(0);
    uint4 kf0 = zero4, kf1 = zero4;
    if (h == 0) { kf0 = *(const uint4*)kb0; kf1 = *(const uint4*)kb1; }
    __syncthreads();

    for (int t = 0; t < NSTR; ++t) {
        uint4 kn0 = zero4, kn1 = zero4;
        if (t + 1 < NSTR) {
            STAGE(t + 1);
            if (h == 0) {
                size_t ko = (size_t)(t + 1) * KB2 * CR;
                kn0 = *(const uint4*)(kb0 + ko);
                kn1 = *(const uint4*)(kb1 + ko);
            }
        }
        CHUNK(i0, kf0);        // keys kh*64 + [0,32)
        CHUNK(i0 ^ 4, kf1);    // keys kh*64 + [32,64)
        __syncthreads();
        kf0 = kn0; kf1 = kn1;
    }
#undef STAGE
#undef CHUNK

    float den = (dn0 + dn1) + (dn2 + dn3);
    den += __shfl_xor(den, 32);

    // ---- kh tree-merge (qh groups serialized, 4 LDS regions) ----
    for (int g = 0; g < 2; ++g) {
        for (int step = 4; step >= 1; step >>= 1) {
            if (qh == g && kh >= step && kh < 2 * step) {
                float* rg = mbuf + (kh - step) * 2080;
                #pragma unroll
                for (int r = 0; r < 16; ++r) {
                    rg[r * 64 + l]        = acc0[r];
                    rg[1024 + r * 64 + l] = acc1[r];
                }
                if (h == 0) rg[2048 + li] = den;
            }
            __syncthreads();
            if (qh == g && kh < step) {
                const float* rg = mbuf + kh * 2080;
                #pragma unroll
                for (int r = 0; r < 16; ++r) {
                    acc0[r] += rg[r * 64 + l];
                    acc1[r] += rg[1024 + r * 64 + l];
                }
                if (h == 0) den += rg[2048 + li];
            }
            __syncthreads();
        }
    }
    if (kh == 0) {
        float* rg = mbuf + qh * 2080;
        #pragma unroll
        for (int r = 0; r < 16; ++r) {
            rg[r * 64 + l]        = acc0[r];
            rg[1024 + r * 64 + l] = acc1[r];
        }
        if (h == 0) rg[2048 + li] = den;
    }
    __syncthreads();

    // ---- epilogue: out = (al/den)*acc + al*b_d[c] + x ----
    {
        const int c   = tid >> 4;
        const int q4  = (tid & 15) * 4;
        const int qhe = q4 >> 5, qlo = q4 & 31;
        const int tile = c >> 5, c5 = c & 31;
        const int hh  = (c5 >> 2) & 1;
        const int r   = (c5 & 3) | ((c5 >> 3) << 2);
        const float* rg = mbuf + qhe * 2080;
        float4 a   = *(const float4*)&rg[tile * 1024 + r * 64 + 32 * hh + qlo];
        float4 dnv = *(const float4*)&rg[2048 + qlo];
        float  al  = alpha[0];
        float  albd = al * b_d[c];
        size_t xo  = ((size_t)(b * CH + c)) * NPOS + q0 + q4;
        float4 xv  = *(const float4*)&x[xo];
        float4 o;
        o.x = a.x * (al / dnv.x) + albd + xv.x;
        o.y = a.y * (al / dnv.y) + albd + xv.y;
        o.z = a.z * (al / dnv.z) + albd + xv.z;
        o.w = a.w * (al / dnv.w) + albd + xv.w;
        *(float4*)&out[xo] = o;
    }
}

extern "C" void kernel_launch(void* const* d_in, const int* in_sizes, int n_in,
                              void* d_out, int out_size, void* d_ws, size_t ws_size,
                              hipStream_t stream) {
    const float* x     = (const float*)d_in[0];
    const float* w_b   = (const float*)d_in[1];
    const float* b_b   = (const float*)d_in[2];
    const float* w_c   = (const float*)d_in[3];
    // d_in[4] = b_c: dropped exactly (adds a per-query logit constant ->
    // softmax-invariant).
    const float* w_d   = (const float*)d_in[5];
    const float* b_d   = (const float*)d_in[6];
    const float* alpha = (const float*)d_in[7];
    float* out = (float*)d_out;

    unsigned short* Qw  = (unsigned short*)d_ws;                 // 256 KB
    unsigned short* Kw  = Qw + (size_t)NB * NPOS * CR;           // 256 KB
    unsigned short* VTw = Kw + (size_t)NB * NPOS * CR;           // 2 MB

    proj_kernel<<<256, 128, 0, stream>>>(x, w_b, b_b, w_c, w_d, Qw, Kw, VTw);
    attn_kernel<<<NB * NPOS / QB, 1024, 0, stream>>>(Qw, Kw, VTw, x, alpha, b_d, out);
}

// Round 7
// 44.842 us; speedup vs baseline: 5.2044x; 1.0600x over previous
//
#include <hip/hip_runtime.h>

// PositionAttentionModule: B=2, C=64, Cr=8, N=8192
// Single-head attention: d_qk=8, d_v=64, seq=8192 per batch.
// out[b,c,m] = alpha * (sum_n softmax_n(Q[m].K[n]) * V[c,n]) + x[b,c,m]
//
// R7: barrier-free attention K-loop. V stored FRAGMENT-MAJOR in global
// (proj emits PV A-fragments directly: unit = kb*256 + (2j+h)*64 + ch,
// 16B per lane), so V-frag loads are coalesced dwordx4 (2 segments/instr)
// straight global->reg from L2. No LDS staging, no in-loop barriers, no
// vmcnt drains. Depth-1 reg double-buffer, unroll-2 with named bufs.
// Softmax floor: 134M v_exp_f32 ~= 2048 trans-instrs/SIMD.

#define NB   2
#define CH   64
#define CR   8
#define NPOS 8192
#define QB   64

typedef __attribute__((ext_vector_type(8)))  __bf16 bf16x8;
typedef __attribute__((ext_vector_type(16))) float  f32x16;

__device__ inline unsigned pk_bf(float lo, float hi) {
    unsigned r;
    asm("v_cvt_pk_bf16_f32 %0, %1, %2" : "=v"(r) : "v"(lo), "v"(hi));
    return r;
}
__device__ inline unsigned short f2bf(float v) {
    return (unsigned short)(pk_bf(v, 0.f) & 0xFFFFu);
}
union U4B { uint4 u; bf16x8 b; };
__device__ inline bf16x8 as_bf(uint4 u) { U4B x; x.u = u; return x.b; }

// ---------------- projection kernel (MFMA) ----------------
// grid 256 x 128 thr (2 waves). Block covers 64 positions; wave covers 32.
// W~[96x64]: rows 0-63 = w_d, 64-71 = w_b*log2e, 72-79 = w_c.
// V output is fragment-major: ushort off = kb*2048 + ks*512 + ch*8 + elem.
__global__ __launch_bounds__(128) void proj_kernel(
    const float* __restrict__ x,
    const float* __restrict__ w_b, const float* __restrict__ b_b,
    const float* __restrict__ w_c,
    const float* __restrict__ w_d,
    unsigned short* __restrict__ Qb, unsigned short* __restrict__ Kb,
    unsigned short* __restrict__ VFb)
{
    __shared__ unsigned short wt[96 * 64];
    const int tid = threadIdx.x;
    const float L2E = 1.4426950408889634f;
    for (int j = tid; j < 4096; j += 128) wt[j] = f2bf(w_d[j]);
    for (int j = tid; j < 512; j += 128) {
        wt[64 * 64 + j] = f2bf(w_b[j] * L2E);
        wt[72 * 64 + j] = f2bf(w_c[j]);
    }
    __syncthreads();

    const int w  = tid >> 6, l = tid & 63, li = l & 31, h = l >> 5;
    const int ng = blockIdx.x * 64 + w * 32;     // global position base
    const int b  = ng >> 13;
    const int n  = ng & (NPOS - 1);

    const f32x16 z16 = {0,0,0,0,0,0,0,0,0,0,0,0,0,0,0,0};

    uint4 af[3][4];
    #pragma unroll
    for (int t = 0; t < 3; ++t)
        #pragma unroll
        for (int ks = 0; ks < 4; ++ks)
            af[t][ks] = *(const uint4*)&wt[(t * 32 + li) * 64 + ks * 16 + 8 * h];

    f32x16 acc0 = z16, acc1 = z16, acc2 = z16;
    #pragma unroll
    for (int ks = 0; ks < 4; ++ks) {
        float xr[8];
        #pragma unroll
        for (int j = 0; j < 8; ++j)
            xr[j] = x[(size_t)(b * CH + ks * 16 + 8 * h + j) * NPOS + n + li];
        uint4 bf = make_uint4(pk_bf(xr[0], xr[1]), pk_bf(xr[2], xr[3]),
                              pk_bf(xr[4], xr[5]), pk_bf(xr[6], xr[7]));
        acc0 = __builtin_amdgcn_mfma_f32_32x32x16_bf16(as_bf(af[0][ks]), as_bf(bf), acc0, 0, 0, 0);
        acc1 = __builtin_amdgcn_mfma_f32_32x32x16_bf16(as_bf(af[1][ks]), as_bf(bf), acc1, 0, 0, 0);
        acc2 = __builtin_amdgcn_mfma_f32_32x32x16_bf16(as_bf(af[2][ks]), as_bf(bf), acc2, 0, 0, 0);
    }

    // V epilogue -> fragment-major. Lane holds key=li (elem li&7, slot ks(li)),
    // channels crow / 32+crow.
    {
        const int kb = n >> 5;
        const int ks = ((li >> 4) << 1) | ((li >> 3) & 1);
        unsigned short* vf = VFb + (size_t)b * NPOS * CH
                           + (size_t)kb * 2048 + ks * 512 + (li & 7);
        #pragma unroll
        for (int r = 0; r < 16; ++r) {
            int crow = (r & 3) + 8 * (r >> 2) + 4 * h;
            vf[crow * 8]        = f2bf(acc0[r]);
            vf[(32 + crow) * 8] = f2bf(acc1[r]);
        }
    }

    // Q/K epilogue: acc2 r0..3 -> Q d=(r)+4h; r4..7 -> K d=(r-4)+4h
    {
        float bb0 = b_b[4 * h + 0] * L2E, bb1 = b_b[4 * h + 1] * L2E;
        float bb2 = b_b[4 * h + 2] * L2E, bb3 = b_b[4 * h + 3] * L2E;
        unsigned q0p = pk_bf(acc2[0] + bb0, acc2[1] + bb1);
        unsigned q1p = pk_bf(acc2[2] + bb2, acc2[3] + bb3);
        unsigned k0p = pk_bf(acc2[4], acc2[5]);
        unsigned k1p = pk_bf(acc2[6], acc2[7]);
        unsigned qa0 = q0p, qb0 = q0p, qa1 = q1p, qb1 = q1p;
        asm("v_permlane32_swap_b32 %0, %1" : "+v"(qa0), "+v"(qb0));
        asm("v_permlane32_swap_b32 %0, %1" : "+v"(qa1), "+v"(qb1));
        unsigned ka0 = k0p, kb0 = k0p, ka1 = k1p, kb1 = k1p;
        asm("v_permlane32_swap_b32 %0, %1" : "+v"(ka0), "+v"(kb0));
        asm("v_permlane32_swap_b32 %0, %1" : "+v"(ka1), "+v"(kb1));
        if (h == 0) {
            *(uint4*)(Qb + (size_t)(b * NPOS + n + li) * CR) = make_uint4(qa0, qa1, qb0, qb1);
            *(uint4*)(Kb + (size_t)(b * NPOS + n + li) * CR) = make_uint4(ka0, ka1, kb0, kb1);
        }
    }
}

// ---------------- fused MFMA flash-attention (barrier-free loop) ----------------
// grid = 256 blocks, 1024 threads = 16 waves = (qh in {0,1}, kh in {0..7}).
// Wave (qh,kh): 32 queries, keys [kh*1024, kh*1024+1024) as 32 chunks of 32.
__global__ __launch_bounds__(1024, 4) void attn_kernel(
    const unsigned short* __restrict__ Qb, const unsigned short* __restrict__ Kb,
    const unsigned short* __restrict__ VFb, const float* __restrict__ x,
    const float* __restrict__ alpha, const float* __restrict__ b_d,
    float* __restrict__ out)
{
    __shared__ float mbuf[4 * 2080];   // merge regions only (no loop LDS)

    const int tid = threadIdx.x;
    const int w   = tid >> 6;
    const int l   = tid & 63;
    const int li  = l & 31;
    const int h   = l >> 5;
    const int qh  = w & 1;
    const int kh  = w >> 1;
    const int blk = (blockIdx.x & 7) * 32 + (blockIdx.x >> 3);   // XCD swizzle
    const int b   = blk >> 7;
    const int q0  = (blk & 127) * QB;
    const int m   = q0 + 32 * qh + li;

    const f32x16 z16 = {0,0,0,0,0,0,0,0,0,0,0,0,0,0,0,0};
    const uint4 zero4 = make_uint4(0, 0, 0, 0);

    uint4 qf = zero4;
    if (h == 0) qf = *(const uint4*)(Qb + ((size_t)b * NPOS + m) * CR);

    f32x16 acc0 = z16, acc1 = z16;
    float dn0 = 0.f, dn1 = 0.f, dn2 = 0.f, dn3 = 0.f;

    // K rows: wave keys = kh*1024 + cc*32 + li
    const unsigned short* kbp = Kb + ((size_t)b * NPOS + kh * 1024 + li) * CR;
    // V fragments: ushort off = kb*2048 + (2j+h)*512 + (32tc+li)*8
    const unsigned short* vfb = VFb + (size_t)b * NPOS * CH
                              + (size_t)kh * 32 * 2048 + h * 512 + li * 8;

#define LOADS(CC, KF, A00, A01, A10, A11) {                        \
    const unsigned short* vp_ = vfb + (size_t)(CC) * 2048;         \
    A00 = *(const uint4*)(vp_);                                    \
    A01 = *(const uint4*)(vp_ + 1024);                             \
    A10 = *(const uint4*)(vp_ + 256);                              \
    A11 = *(const uint4*)(vp_ + 1280);                             \
    if (h == 0) KF = *(const uint4*)(kbp + (size_t)(CC) * 32 * CR); }

#define COMPUTE(KF, A00, A01, A10, A11) {                                                     \
    f32x16 sv = __builtin_amdgcn_mfma_f32_32x32x16_bf16(as_bf(KF), as_bf(qf), z16, 0, 0, 0);  \
    float p0_, p1_;                                                                           \
    unsigned pa0, pa1, pb0, pb1, pc0, pc1, pd0, pd1;                                          \
    p0_ = __builtin_amdgcn_exp2f(sv[0]);  p1_ = __builtin_amdgcn_exp2f(sv[1]);                \
    dn0 += p0_ + p1_;  pa0 = pk_bf(p0_, p1_);                                                 \
    p0_ = __builtin_amdgcn_exp2f(sv[2]);  p1_ = __builtin_amdgcn_exp2f(sv[3]);                \
    dn1 += p0_ + p1_;  pa1 = pk_bf(p0_, p1_);                                                 \
    p0_ = __builtin_amdgcn_exp2f(sv[4]);  p1_ = __builtin_amdgcn_exp2f(sv[5]);                \
    dn2 += p0_ + p1_;  pb0 = pk_bf(p0_, p1_);                                                 \
    p0_ = __builtin_amdgcn_exp2f(sv[6]);  p1_ = __builtin_amdgcn_exp2f(sv[7]);                \
    dn3 += p0_ + p1_;  pb1 = pk_bf(p0_, p1_);                                                 \
    p0_ = __builtin_amdgcn_exp2f(sv[8]);  p1_ = __builtin_amdgcn_exp2f(sv[9]);                \
    dn0 += p0_ + p1_;  pc0 = pk_bf(p0_, p1_);                                                 \
    p0_ = __builtin_amdgcn_exp2f(sv[10]); p1_ = __builtin_amdgcn_exp2f(sv[11]);               \
    dn1 += p0_ + p1_;  pc1 = pk_bf(p0_, p1_);                                                 \
    p0_ = __builtin_amdgcn_exp2f(sv[12]); p1_ = __builtin_amdgcn_exp2f(sv[13]);               \
    dn2 += p0_ + p1_;  pd0 = pk_bf(p0_, p1_);                                                 \
    p0_ = __builtin_amdgcn_exp2f(sv[14]); p1_ = __builtin_amdgcn_exp2f(sv[15]);               \
    dn3 += p0_ + p1_;  pd1 = pk_bf(p0_, p1_);                                                 \
    asm("v_permlane32_swap_b32 %0, %1" : "+v"(pa0), "+v"(pb0));                               \
    asm("v_permlane32_swap_b32 %0, %1" : "+v"(pa1), "+v"(pb1));                               \
    asm("v_permlane32_swap_b32 %0, %1" : "+v"(pc0), "+v"(pd0));                               \
    asm("v_permlane32_swap_b32 %0, %1" : "+v"(pc1), "+v"(pd1));                               \
    uint4 BA = make_uint4(pa0, pa1, pb0, pb1);                                                \
    uint4 BB = make_uint4(pc0, pc1, pd0, pd1);                                                \
    acc0 = __builtin_amdgcn_mfma_f32_32x32x16_bf16(as_bf(A00), as_bf(BA), acc0, 0, 0, 0);     \
    acc0 = __builtin_amdgcn_mfma_f32_32x32x16_bf16(as_bf(A01), as_bf(BB), acc0, 0, 0, 0);     \
    acc1 = __builtin_amdgcn_mfma_f32_32x32x16_bf16(as_bf(A10), as_bf(BA), acc1, 0, 0, 0);     \
    acc1 = __builtin_amdgcn_mfma_f32_32x32x16_bf16(as_bf(A11), as_bf(BB), acc1, 0, 0, 0); }

    uint4 kfA = zero4, a00A, a01A, a10A, a11A;
    uint4 kfB = zero4, a00B, a01B, a10B, a11B;
    LOADS(0, kfA, a00A, a01A, a10A, a11A);

    for (int cc = 0; cc < 32; cc += 2) {
        LOADS(cc + 1, kfB, a00B, a01B, a10B, a11B);
        COMPUTE(kfA, a00A, a01A, a10A, a11A);
        if (cc + 2 < 32) LOADS(cc + 2, kfA, a00A, a01A, a10A, a11A);
        COMPUTE(kfB, a00B, a01B, a10B, a11B);
    }
#undef LOADS
#undef COMPUTE

    float den = (dn0 + dn1) + (dn2 + dn3);
    den += __shfl_xor(den, 32);

    // ---- kh tree-merge (qh groups serialized, 4 LDS regions) ----
    for (int g = 0; g < 2; ++g) {
        for (int step = 4; step >= 1; step >>= 1) {
            if (qh == g && kh >= step && kh < 2 * step) {
                float* rg = mbuf + (kh - step) * 2080;
                #pragma unroll
                for (int r = 0; r < 16; ++r) {
                    rg[r * 64 + l]        = acc0[r];
                    rg[1024 + r * 64 + l] = acc1[r];
                }
                if (h == 0) rg[2048 + li] = den;
            }
            __syncthreads();
            if (qh == g && kh < step) {
                const float* rg = mbuf + kh * 2080;
                #pragma unroll
                for (int r = 0; r < 16; ++r) {
                    acc0[r] += rg[r * 64 + l];
                    acc1[r] += rg[1024 + r * 64 + l];
                }
                if (h == 0) den += rg[2048 + li];
            }
            __syncthreads();
        }
    }
    if (kh == 0) {
        float* rg = mbuf + qh * 2080;
        #pragma unroll
        for (int r = 0; r < 16; ++r) {
            rg[r * 64 + l]        = acc0[r];
            rg[1024 + r * 64 + l] = acc1[r];
        }
        if (h == 0) rg[2048 + li] = den;
    }
    __syncthreads();

    // ---- epilogue: out = (al/den)*acc + al*b_d[c] + x ----
    {
        const int c   = tid >> 4;
        const int q4  = (tid & 15) * 4;
        const int qhe = q4 >> 5, qlo = q4 & 31;
        const int tile = c >> 5, c5 = c & 31;
        const int hh  = (c5 >> 2) & 1;
        const int r   = (c5 & 3) | ((c5 >> 3) << 2);
        const float* rg = mbuf + qhe * 2080;
        float4 a   = *(const float4*)&rg[tile * 1024 + r * 64 + 32 * hh + qlo];
        float4 dnv = *(const float4*)&rg[2048 + qlo];
        float  al  = alpha[0];
        float  albd = al * b_d[c];
        size_t xo  = ((size_t)(b * CH + c)) * NPOS + q0 + q4;
        float4 xv  = *(const float4*)&x[xo];
        float4 o;
        o.x = a.x * (al / dnv.x) + albd + xv.x;
        o.y = a.y * (al / dnv.y) + albd + xv.y;
        o.z = a.z * (al / dnv.z) + albd + xv.z;
        o.w = a.w * (al / dnv.w) + albd + xv.w;
        *(float4*)&out[xo] = o;
    }
}

extern "C" void kernel_launch(void* const* d_in, const int* in_sizes, int n_in,
                              void* d_out, int out_size, void* d_ws, size_t ws_size,
                              hipStream_t stream) {
    const float* x     = (const float*)d_in[0];
    const float* w_b   = (const float*)d_in[1];
    const float* b_b   = (const float*)d_in[2];
    const float* w_c   = (const float*)d_in[3];
    // d_in[4] = b_c: dropped exactly (softmax-invariant per-query constant).
    const float* w_d   = (const float*)d_in[5];
    const float* b_d   = (const float*)d_in[6];
    const float* alpha = (const float*)d_in[7];
    float* out = (float*)d_out;

    unsigned short* Qw  = (unsigned short*)d_ws;                 // 256 KB
    unsigned short* Kw  = Qw + (size_t)NB * NPOS * CR;           // 256 KB
    unsigned short* VFw = Kw + (size_t)NB * NPOS * CR;           // 2 MB (frag-major)

    proj_kernel<<<256, 128, 0, stream>>>(x, w_b, b_b, w_c, w_d, Qw, Kw, VFw);
    attn_kernel<<<NB * NPOS / QB, 1024, 0, stream>>>(Qw, Kw, VFw, x, alpha, b_d, out);
}